// Round 8
// baseline (255.025 us; speedup 1.0000x reference)
//
#include <hip/hip_runtime.h>
#include <stdint.h>

// Cost volume: out[b,k,h,w] = (1/81) * sum_c x1[b,c,h,w] * x2[b,c,h-i,w-j]
// k = (9i+j) mod 81, i,j in [-4,4], zero-padded x2. B=4 C=128 H=128 W=256 fp32.
//
// R13: overlap + request-byte cut. R5-R12 cycle accounting closes: phases
// are fully SERIAL (sum-of-pipes = measured 11.6 kcyc/chunk-iter; VMEM idle
// during compute, compute idle during staging; co-resident blocks phase-
// lock, R12). Fix = intra-block overlap: LDS DOUBLE buffer + counted BAR
// (R6 had dbuf but drained vmcnt; R9 had counted BAR but single buffer;
// never combined until now) with compute-FIRST order per iteration:
//   COMPUTE(bufA)            // MFMA+ds_read; next chunk streams meanwhile
//   CONVSET(bufB)            // vmcnt wait lands AFTER compute
//   LOADSET(chunk+2)         // back in flight across the barrier
//   BAR()                    // lgkmcnt-only: loads stay outstanding
// Request bytes 308->235 MB: one block per 8h x 32w tile, each wave all
// 9 i's (acc0/acc1[9] = 72 f32 statically indexed; watch VGPR<=128).
// 512 blocks of 1024 thr; LDS 2 x 76 KB = 152.25 KB -> 1 block/CU.
// Kept verbatim: Toeplitz frag math (R11-verified), KSTR=38 odd-word
// strides, cvt_pk_bf16, setprio, epilogue scratch [hl][m][kk] 8q+ja banks.
//
// Toeplitz: D[m][n] = sum_c x1[c, w0+m] * x2[c, h-i, w0-4+n], out(w0+m, j)
//   = D[m][m+4-j]; per m-half a 24-col window = 2x mfma_f32_16x16x32_bf16
//   (B_ROW holds 48 col slots; cols 40+ junk, ja-guard never stores them).

#define HH 128
#define WW 256
#define HW 32768
#define DD 81
#define NT 1024

typedef __attribute__((ext_vector_type(8))) short short8;
typedef __attribute__((ext_vector_type(4))) float float4v;

// staging geometry (ushorts)
#define KSTR 38          // 32 bf16 ch + 6 pad; word-stride 19 (odd)
#define A_ROW 1220       // 32 m * 38 + 4 pad
#define B_ROW 1826       // 48 col * 38 + 2 pad
#define B_BASE 9760      // A region = 8 * 1220
#define BUF_USH 38976    // 9760 + 16*1826  (16 staged x2 rows: h0-4..h0+11)
#define SMEM_USH 77952   // 2 buffers = 155904 B -> 1 block/CU
// epilogue scratch: [8 hl][32 m][81 kl], m-stride 82, hl-stride 2625 floats
#define EP_M 82
#define EP_H 2625        // 32*82 + 1; total 21000 f = 84 KB < 152 KB

// LDS-only barrier: does NOT drain vmcnt (prefetch stays in flight).
#define BAR()                                                \
  {                                                          \
    asm volatile("s_waitcnt lgkmcnt(0)" ::: "memory");       \
    __builtin_amdgcn_s_barrier();                            \
    asm volatile("" ::: "memory");                           \
  }

__device__ __forceinline__ uint32_t cvt_pk_bf16(float lo, float hi) {
  uint32_t r;
  asm("v_cvt_pk_bf16_f32 %0, %1, %2" : "=v"(r) : "v"(lo), "v"(hi));
  return r;
}

__global__ __launch_bounds__(NT, 4) void cost_volume_kernel(
    const float* __restrict__ x1, const float* __restrict__ x2,
    float* __restrict__ out, const float* __restrict__ zws) {
  __shared__ unsigned short smem[SMEM_USH];

  const int b = blockIdx.z;
  const int w0 = blockIdx.x * 32;
  const int h0 = blockIdx.y * 8;
  const int t = threadIdx.x;
  const int wid = t >> 6;
  const int hl = wid & 7;
  const int mtw = wid >> 3;  // m-half: m in [16*mtw, 16*mtw+16)
  const int lane = t & 63;
  const int n16 = lane & 15;
  const int quad = lane >> 4;
  const bool has3 = (t < 512);  // slot 3 valid for waves 0-7 (wave-uniform)

  const float* x1b = x1 + (size_t)b * 128 * HW;
  const float* x2b = x2 + (size_t)b * 128 * HW;

  // ---- staging task decode (chunk-invariant). 3584 c-pair tasks/chunk:
  //   A (x1): 1024 = cp16 x row8 x f4 8 ; B (x2): 2560 = cp16 x row16 x f4 10
  // slots: s0 = A(t); s1 = B(t); s2 = B(t+1024); s3 = B(t+2048), t<512 only.
  const float* tbase[4];
  int tgoff[4], tlds[4];
  bool tok[4];
  {  // s0: x1 rows h0..h0+7, 128B contiguous per (row,cp)
    const int cp = t >> 6, rem = t & 63, row = rem >> 3, f4 = rem & 7;
    tbase[0] = x1b;
    tgoff[0] = (h0 + row) * WW + w0 + 4 * f4 + 2 * cp * HW;
    tlds[0] = row * A_ROW + f4 * (4 * KSTR) + 2 * cp;
    tok[0] = true;
  }
#pragma unroll
  for (int s = 1; s < 4; ++s) {  // x2 rows h0-4..h0+11, 160B per (row,cp)
    const int tb = (s - 1) * 1024 + t;  // < 2560 when slot participates
    const int cp = tb / 160, rem = tb - 160 * cp, row = rem / 10,
              f4 = rem - 10 * row;
    const int h2 = h0 - 4 + row;
    const int wg = w0 - 4 + 4 * f4;
    tbase[s] = x2b;
    tgoff[s] = h2 * WW + wg + 2 * cp * HW;
    tlds[s] = B_BASE + row * B_ROW + f4 * (4 * KSTR) + 2 * cp;
    tok[s] = ((unsigned)h2 < (unsigned)HH) && ((unsigned)wg <= (unsigned)(WW - 4));
  }

  float4v acc0[9], acc1[9];
#pragma unroll
  for (int ii = 0; ii < 9; ++ii) {
    acc0[ii] = (float4v){0.f, 0.f, 0.f, 0.f};
    acc1[ii] = (float4v){0.f, 0.f, 0.f, 0.f};
  }

  float4 va[4], vb[4];

#define LOADSET(C0)                                                            \
  {                                                                            \
    _Pragma("unroll") for (int s = 0; s < 4; ++s) {                            \
      if (s < 3 || has3) {                                                     \
        const float* p =                                                       \
            tok[s] ? tbase[s] + (size_t)(C0)*HW + tgoff[s] : zws;              \
        const float* q = tok[s] ? p + HW : zws;                                \
        va[s] = *(const float4*)p;                                             \
        vb[s] = *(const float4*)q;                                             \
      }                                                                        \
    }                                                                          \
  }

#define CONVSET(BUFSEL)                                                        \
  {                                                                            \
    _Pragma("unroll") for (int s = 0; s < 4; ++s) {                            \
      if (s < 3 || has3) {                                                     \
        unsigned short* dst = smem + (BUFSEL)*BUF_USH + tlds[s];               \
        const float4 fa = va[s];                                               \
        const float4 fb = vb[s];                                               \
        *(uint32_t*)(dst + 0 * KSTR) = cvt_pk_bf16(fa.x, fb.x);                \
        *(uint32_t*)(dst + 1 * KSTR) = cvt_pk_bf16(fa.y, fb.y);                \
        *(uint32_t*)(dst + 2 * KSTR) = cvt_pk_bf16(fa.z, fb.z);                \
        *(uint32_t*)(dst + 3 * KSTR) = cvt_pk_bf16(fa.w, fb.w);                \
      }                                                                        \
    }                                                                          \
  }

#define COMPUTE(BUFSEL)                                                        \
  {                                                                            \
    const unsigned short* buf = smem + (BUFSEL)*BUF_USH;                       \
    const short8 a = *(const short8*)(buf + hl * A_ROW +                       \
                                      (16 * mtw + n16) * KSTR + quad * 8);     \
    __builtin_amdgcn_s_setprio(1);                                             \
    _Pragma("unroll") for (int ii = 0; ii < 9; ++ii) {                         \
      const int r = hl + 8 - ii; /* staged row for i = ii-4 */                 \
      const unsigned short* bp =                                               \
          buf + B_BASE + r * B_ROW + (16 * mtw + n16) * KSTR + quad * 8;       \
      const short8 b0 = *(const short8*)(bp);                                  \
      const short8 b1 = *(const short8*)(bp + 16 * KSTR);                      \
      acc0[ii] =                                                               \
          __builtin_amdgcn_mfma_f32_16x16x32_bf16(a, b0, acc0[ii], 0, 0, 0);   \
      acc1[ii] =                                                               \
          __builtin_amdgcn_mfma_f32_16x16x32_bf16(a, b1, acc1[ii], 0, 0, 0);   \
    }                                                                          \
    __builtin_amdgcn_s_setprio(0);                                             \
  }

  // ---- pipelined main loop: 4 chunks of 32 ch, double buffer, 1 BAR/iter --
  LOADSET(0);
  CONVSET(0);     // stage c0 -> buf0 (waits only its own loads)
  LOADSET(32);    // c1 in flight
  BAR();

  COMPUTE(0);     // c0; c1 streams in under the MFMAs
  CONVSET(1);     // stage c1 -> buf1
  LOADSET(64);    // c2 in flight
  BAR();

  COMPUTE(1);     // c1
  CONVSET(0);     // stage c2 -> buf0
  LOADSET(96);    // c3 in flight
  BAR();

  COMPUTE(0);     // c2
  CONVSET(1);     // stage c3 -> buf1
  BAR();

  COMPUTE(1);     // c3
  BAR();  // all frag reads done; reuse smem as fp32 scratch

  // ---- epilogue: scatter D to LDS scratch [hl][m 32][kl 81], coalesced out -
  float* scratch = (float*)smem;  // 21000 floats = 84000 B < 155904 B
  const float sc = 1.0f / 81.0f;
#pragma unroll
  for (int ii = 0; ii < 9; ++ii) {  // iabs = ii (i = ii - 4)
    const float av0[4] = {acc0[ii].x, acc0[ii].y, acc0[ii].z, acc0[ii].w};
    const float av1[4] = {acc1[ii].x, acc1[ii].y, acc1[ii].z, acc1[ii].w};
#pragma unroll
    for (int reg = 0; reg < 4; ++reg) {
      const int mr = quad * 4 + reg;
      const int m = 16 * mtw + mr;
      // n-tile 0 (n = 16*mtw + n16): ja = mr + 8 - n16
      {
        const unsigned ja = (unsigned)(mr + 8 - n16);
        if (ja < 9u)
          scratch[hl * EP_H + m * EP_M + ii * 9 + (int)ja] = av0[reg] * sc;
      }
      // n-tile 1 (n = 16*mtw + 16 + n16): ja = mr - 8 - n16
      {
        const unsigned ja = (unsigned)(mr - 8 - n16);
        if (ja < 9u)
          scratch[hl * EP_H + m * EP_M + ii * 9 + (int)ja] = av1[reg] * sc;
      }
    }
  }
  BAR();

  // write-out: f -> (kl, hlx, mg); 4 scalar LDS reads (banks hlx+8mg+18e+kl:
  // exactly 2 lanes/bank) -> 128B-contiguous global stores per (kl,row).
  for (int f = t; f < 5184; f += NT) {  // 81 kl * 8 hlx * 8 mg
    const int mg = f & 7;
    const int hlx = (f >> 3) & 7;
    const int kl = f >> 6;  // wave-uniform
    float4 v;
    v.x = scratch[hlx * EP_H + (4 * mg + 0) * EP_M + kl];
    v.y = scratch[hlx * EP_H + (4 * mg + 1) * EP_M + kl];
    v.z = scratch[hlx * EP_H + (4 * mg + 2) * EP_M + kl];
    v.w = scratch[hlx * EP_H + (4 * mg + 3) * EP_M + kl];
    const int kk = (kl + 41) % 81;  // k = 9(ii-4) + (ja-4) mod 81
    *(float4*)(out + (((size_t)b * DD + kk) * HH + (h0 + hlx)) * WW + w0 +
               4 * mg) = v;
  }
}

extern "C" void kernel_launch(void* const* d_in, const int* in_sizes, int n_in,
                              void* d_out, int out_size, void* d_ws,
                              size_t ws_size, hipStream_t stream) {
  const float* x1 = (const float*)d_in[0];
  const float* x2 = (const float*)d_in[1];
  float* out = (float*)d_out;

  // zero 256 B of workspace: OOB staging lanes read zeros from here
  hipMemsetAsync(d_ws, 0, 256, stream);

  // 8 w-tiles x 16 h-tiles x 4 batches = 512 blocks of 1024 threads
  dim3 grid(8, 16, 4);
  dim3 block(NT);
  hipLaunchKernelGGL(cost_volume_kernel, grid, block, 0, stream, x1, x2, out,
                     (const float*)d_ws);
}

// Round 9
// 209.698 us; speedup vs baseline: 1.2162x; 1.2162x over previous
//
#include <hip/hip_runtime.h>
#include <stdint.h>

// Cost volume: out[b,k,h,w] = (1/81) * sum_c x1[b,c,h,w] * x2[b,c,h-i,w-j]
// k = (9i+j) mod 81, i,j in [-4,4], zero-padded x2. B=4 C=128 H=128 W=256 fp32.
//
// R14: producer/consumer wave specialization (guide §Composed models: the
// path past barrier-phase-lock). 10 rounds established: every all-wave
// lockstep structure = ~87us (sum-of-phases serial, R12 accounting);
// R8 proved HBM isn't the constraint (FETCH 194->80MB via L2, time flat);
// R13/R10 proved the register envelope is acc<=40 + <=3 load slots.
//  - Block 1024 thr = 16 waves: wid 0..11 CONSUMERS (hl 0..3 x i-third g,
//    R12's verified math, acc 3i x 2nt x 4 = 24 f32, ds_read+MFMA only);
//    wid 12..15 PRODUCERS (one per SIMD, no acc -> 6 load slots = 48 VGPR
//    affordable; load+cvt_pk+ds_write only).
//  - LDS double buffer 2 x 18176 ush = 72.7 KB; ONE lgkmcnt-only BAR per
//    chunk. Between BARs: producers stage chunk k+1 -> buf[(k+1)&1] while
//    consumers compute chunk k <- buf[k&1]. Per SIMD: 1 producer wave's
//    VMEM/VALU overlaps 3 consumer waves' LDS/MFMA (m114 co-schedule).
//  - Producer pipeline 2-deep: loads for chunk k+2 issued right after
//    chunk k+1's regs are consumed; vmcnt waits are producer-only.
//  - Kept verbatim from R12 (passed): Toeplitz frag math, KSTR=40 strides,
//    cvt_pk_bf16, setprio, epilogue scratch [hl][m][kk] EP_M 82 / EP_H 1313.
//
// Toeplitz: D[m][n] = sum_c x1[c, w0+m] * x2[c, h-i, w0-4+n], out(w0+m, j)
//   = D[m][m+4-j]; window 24 cols = 2x mfma_f32_16x16x32_bf16 (tile1 cols
//   24..31 junk, ja-guard never stores).
// i-thirds: g=0: i{-4..-2}, g=1: i{-1..1}, g=2: i{2..4}; i = 3g-4+ii.
// Staged B row r = hl + (8-3g) - ii in [0,12); h2 = h0 - 4 + r.

#define HH 128
#define WW 256
#define HW 32768
#define DD 81
#define NT 1024

typedef __attribute__((ext_vector_type(8))) short short8;
typedef __attribute__((ext_vector_type(4))) float float4v;

// staging geometry (ushorts) -- per buffer
#define KSTR 40          // 32 bf16 ch + 8 pad
#define A_ROW 648        // 16 m * 40 + 8 pad
#define B_BASE 2592      // A region = 4 rows * 648
#define B_ROW 1288       // 32 col slots * 40 + 8 pad (cols 24+ junk-alloc)
#define DUMP_USH 18048   // invalid staging tasks write here
#define BUF_USH 18176    // per-buffer ushorts (36352 B)
#define SMEM_USH 36352   // 2 buffers = 72704 B
// epilogue scratch: [4 hl][16 m][81 kk], m-stride 82, hl-stride 1313 floats
#define EP_M 82
#define EP_H 1313        // scratch 5252 f = 21008 B, overlays buf0

// LDS-only barrier: does NOT drain vmcnt (producer prefetch stays in flight).
#define BAR()                                                \
  {                                                          \
    asm volatile("s_waitcnt lgkmcnt(0)" ::: "memory");       \
    __builtin_amdgcn_s_barrier();                            \
    asm volatile("" ::: "memory");                           \
  }

__device__ __forceinline__ uint32_t cvt_pk_bf16(float lo, float hi) {
  uint32_t r;
  asm("v_cvt_pk_bf16_f32 %0, %1, %2" : "=v"(r) : "v"(lo), "v"(hi));
  return r;
}

__global__ __launch_bounds__(NT, 4) void cost_volume_kernel(
    const float* __restrict__ x1, const float* __restrict__ x2,
    float* __restrict__ out, const float* __restrict__ zws) {
  __shared__ unsigned short smem[SMEM_USH];

  const int b = blockIdx.z;
  const int h0 = blockIdx.y * 4;
  const int w0 = blockIdx.x * 16;
  const int t = threadIdx.x;
  const int wid = t >> 6;
  const bool producer = (wid >= 12);
  // consumer role decode (junk-but-unused for producers)
  const int hl = wid & 3;
  const int g = wid >> 2;      // 0..2 for consumers
  const int roff = 8 - 3 * g;  // staged B row = hl + roff - ii
  const int lane = t & 63;
  const int n16 = lane & 15;
  const int quad = lane >> 4;

  const float* x1b = x1 + (size_t)b * 128 * HW;
  const float* x2b = x2 + (size_t)b * 128 * HW;

  // ---- producer staging decode: 1408 c-pair tasks/chunk over 256 threads,
  // 6 slots each (slot 5 valid for pt<128). A: 256 = cp16 x row4 x f4 4;
  // B: 1152 = cp16 x row12 x f4 6. (Arrays junk for consumers; never used.)
  const int pt = t & 255;
  const float* tbase[6];
  int tgoff[6], tlds[6];
  bool tok[6];
#pragma unroll
  for (int s = 0; s < 6; ++s) {
    const int tau = pt + 256 * s;
    if (tau < 256) {  // folds to s==0
      const int cp = tau >> 4, rem = tau & 15, row = rem >> 2, f4 = rem & 3;
      tbase[s] = x1b;
      tgoff[s] = (h0 + row) * WW + w0 + 4 * f4 + 2 * cp * HW;
      tlds[s] = row * A_ROW + f4 * (4 * KSTR) + 2 * cp;
      tok[s] = true;
    } else {
      const int tb = tau - 256;  // valid < 1152
      const int cp = tb / 72, rem = tb - 72 * cp, row = rem / 6,
                f4 = rem - 6 * row;
      const int h2 = h0 - 4 + row;
      const int wg = w0 - 4 + 4 * f4;
      const bool inb = (tb < 1152) && ((unsigned)h2 < (unsigned)HH) &&
                       ((unsigned)wg <= (unsigned)(WW - 4));
      tbase[s] = x2b;
      tgoff[s] = inb ? (h2 * WW + wg + 2 * cp * HW) : 0;
      tlds[s] = (tb < 1152)
                    ? (B_BASE + row * B_ROW + f4 * (4 * KSTR) + 2 * cp)
                    : DUMP_USH;
      tok[s] = inb;  // OOB-but-real slots write zeros (padding semantics)
    }
  }

  float4v acc[3][2];
#pragma unroll
  for (int ii = 0; ii < 3; ++ii) {
    acc[ii][0] = (float4v){0.f, 0.f, 0.f, 0.f};
    acc[ii][1] = (float4v){0.f, 0.f, 0.f, 0.f};
  }

  float4 va[6], vb[6];

// issue the 12 float4 loads for chunk starting at channel C0 (producer only)
#define P_ISSUE(C0)                                                            \
  {                                                                            \
    _Pragma("unroll") for (int s = 0; s < 6; ++s) {                            \
      const float* p =                                                         \
          tok[s] ? tbase[s] + (size_t)(C0)*HW + tgoff[s] : zws;                \
      const float* q = tok[s] ? p + HW : zws;                                  \
      va[s] = *(const float4*)p;                                               \
      vb[s] = *(const float4*)q;                                               \
    }                                                                          \
  }

// convert + transposed LDS write of the held chunk (producer only)
#define P_WRITE(BUFSEL)                                                        \
  {                                                                            \
    _Pragma("unroll") for (int s = 0; s < 6; ++s) {                            \
      unsigned short* dst = smem + (BUFSEL)*BUF_USH + tlds[s];                 \
      const float4 fa = va[s];                                                 \
      const float4 fb = vb[s];                                                 \
      *(uint32_t*)(dst + 0 * KSTR) = cvt_pk_bf16(fa.x, fb.x);                  \
      *(uint32_t*)(dst + 1 * KSTR) = cvt_pk_bf16(fa.y, fb.y);                  \
      *(uint32_t*)(dst + 2 * KSTR) = cvt_pk_bf16(fa.z, fb.z);                  \
      *(uint32_t*)(dst + 3 * KSTR) = cvt_pk_bf16(fa.w, fb.w);                  \
    }                                                                          \
  }

// consumer MFMA work on one staged chunk
#define COMPUTE(BUFSEL)                                                        \
  {                                                                            \
    const unsigned short* buf = smem + (BUFSEL)*BUF_USH;                       \
    const short8 a =                                                           \
        *(const short8*)(buf + hl * A_ROW + n16 * KSTR + quad * 8);            \
    __builtin_amdgcn_s_setprio(1);                                             \
    _Pragma("unroll") for (int ii = 0; ii < 3; ++ii) {                         \
      const int r = hl + roff - ii;                                            \
      const unsigned short* bp =                                               \
          buf + B_BASE + r * B_ROW + n16 * KSTR + quad * 8;                    \
      const short8 b0 = *(const short8*)(bp);                                  \
      const short8 b1 = *(const short8*)(bp + 16 * KSTR);                      \
      acc[ii][0] =                                                             \
          __builtin_amdgcn_mfma_f32_16x16x32_bf16(a, b0, acc[ii][0], 0, 0, 0); \
      acc[ii][1] =                                                             \
          __builtin_amdgcn_mfma_f32_16x16x32_bf16(a, b1, acc[ii][1], 0, 0, 0); \
    }                                                                          \
    __builtin_amdgcn_s_setprio(0);                                             \
  }

  // ---- role-split pipeline: 4 chunks of 32 ch, double buffer, 1 BAR/chunk --
  // prologue: producers stage c0 -> buf0, issue c1
  if (producer) {
    P_ISSUE(0);
    P_WRITE(0);   // waits own vmcnt only
    P_ISSUE(32);  // c1 in flight
  }
  BAR();  // c0 visible

  // k=0: consumers compute c0 (buf0); producers stage c1 -> buf1, issue c2
  if (producer) {
    P_WRITE(1);
    P_ISSUE(64);
  } else {
    COMPUTE(0);
  }
  BAR();

  // k=1: compute c1 (buf1); stage c2 -> buf0 (c0 reads done at k=0 BAR)
  if (producer) {
    P_WRITE(0);
    P_ISSUE(96);
  } else {
    COMPUTE(1);
  }
  BAR();

  // k=2: compute c2 (buf0); stage c3 -> buf1
  if (producer) {
    P_WRITE(1);
  } else {
    COMPUTE(0);
  }
  BAR();

  // k=3: compute c3 (buf1); producers idle
  if (!producer) {
    COMPUTE(1);
  }
  BAR();  // all frag reads done; reuse smem as fp32 scratch

  // ---- epilogue: consumers scatter D to scratch [hl][m][kk]; all write out -
  float* scratch = (float*)smem;  // 5252 floats = 21008 B < 72704 B
  if (!producer) {
    const float sc = 1.0f / 81.0f;
#pragma unroll
    for (int ii = 0; ii < 3; ++ii) {
      const int iabs = 3 * g + ii;  // i + 4
      const float av0[4] = {acc[ii][0].x, acc[ii][0].y, acc[ii][0].z,
                            acc[ii][0].w};
      const float av1[4] = {acc[ii][1].x, acc[ii][1].y, acc[ii][1].z,
                            acc[ii][1].w};
#pragma unroll
      for (int reg = 0; reg < 4; ++reg) {
        const int m = quad * 4 + reg;
        // n-tile 0 (n = n16): ja = m + 8 - n16
        {
          const unsigned ja = (unsigned)(m + 8 - n16);
          if (ja < 9u)
            scratch[hl * EP_H + m * EP_M + iabs * 9 + (int)ja] = av0[reg] * sc;
        }
        // n-tile 1 (n = 16 + n16): ja = m - 8 - n16
        {
          const unsigned ja = (unsigned)(m - 8 - n16);
          if (ja < 9u)
            scratch[hl * EP_H + m * EP_M + iabs * 9 + (int)ja] = av1[reg] * sc;
        }
      }
    }
  }
  BAR();  // scatter visible

  // write-out: f -> (kk81, hlx, m4); 4 scalar LDS reads per float4
  for (int f = t; f < 1296; f += NT) {  // 81 kk * 4 hlx * 4 m4
    const int m4 = f & 3;
    const int hlx = (f >> 2) & 3;
    const int kk81 = f >> 4;
    float4 v;
    v.x = scratch[hlx * EP_H + (4 * m4 + 0) * EP_M + kk81];
    v.y = scratch[hlx * EP_H + (4 * m4 + 1) * EP_M + kk81];
    v.z = scratch[hlx * EP_H + (4 * m4 + 2) * EP_M + kk81];
    v.w = scratch[hlx * EP_H + (4 * m4 + 3) * EP_M + kk81];
    const int kk = (kk81 + 41) % 81;
    *(float4*)(out + (((size_t)b * DD + kk) * HH + (h0 + hlx)) * WW + w0 +
               4 * m4) = v;
  }
}

extern "C" void kernel_launch(void* const* d_in, const int* in_sizes, int n_in,
                              void* d_out, int out_size, void* d_ws,
                              size_t ws_size, hipStream_t stream) {
  const float* x1 = (const float*)d_in[0];
  const float* x2 = (const float*)d_in[1];
  float* out = (float*)d_out;

  // zero 256 B of workspace: OOB staging lanes read zeros from here
  hipMemsetAsync(d_ws, 0, 256, stream);

  // 16 w-tiles x 32 h-tiles x 4 batches = 2048 blocks of 1024 threads
  dim3 grid(16, 32, 4);
  dim3 block(NT);
  hipLaunchKernelGGL(cost_volume_kernel, grid, block, 0, stream, x1, x2, out,
                     (const float*)d_ws);
}